// Round 1
// baseline (232.102 us; speedup 1.0000x reference)
//
#include <hip/hip_runtime.h>
#include <hip/hip_bf16.h>

typedef unsigned short u16;
typedef unsigned int u32;

#define AGT 8
#define NBATCH 32768
#define DDIM 128
#define HEADS 4
#define KDIM 32
#define CC 128        // HEADS*KDIM
#define NT 8
#define MROWS 64      // AGT*NT

typedef float f32x4 __attribute__((ext_vector_type(4)));
typedef __bf16 bf16x8 __attribute__((ext_vector_type(8)));
typedef short s16x8 __attribute__((ext_vector_type(8)));

union FragU { s16x8 s; bf16x8 b; };

__device__ __forceinline__ u16 f2bf(float f) {
  u32 u = __float_as_uint(f);
  u = (u + 0x7FFFu + ((u >> 16) & 1u)) >> 16;
  return (u16)u;
}
__device__ __forceinline__ float bf2f(u16 u) {
  return __uint_as_float(((u32)u) << 16);
}

// Rearrange W[h][k][d] (f32) into bf16 MFMA B-fragment order:
// Wb[(((pj*8+ct)*4+kc)*64+l)*8+b] = W_pj[c>>5][c&31][d],
//   c = ct*16 + (l&15),  d = kc*32 + (b>>2)*16 + ((l>>4)<<2) + (b&3)
__global__ void prep_weights(const float* __restrict__ Wk,
                             const float* __restrict__ Ws,
                             const float* __restrict__ Wv,
                             u16* __restrict__ Wb) {
  int idx = blockIdx.x * 256 + threadIdx.x;
  if (idx >= 3 * 8 * 4 * 64 * 8) return;
  int b  = idx & 7;
  int l  = (idx >> 3) & 63;
  int kc = (idx >> 9) & 3;
  int ct = (idx >> 11) & 7;
  int pj = idx >> 14;
  int c = ct * 16 + (l & 15);
  int h = c >> 5, kk = c & 31;
  int d = kc * 32 + ((b >> 2) << 4) + ((l >> 4) << 2) + (b & 3);
  const float* W = (pj == 0) ? Wk : ((pj == 1) ? Ws : Wv);
  Wb[idx] = f2bf(W[(h * KDIM + kk) * DDIM + d]);
}

__global__ __launch_bounds__(256, 3) void fused_attn(
    const float* __restrict__ qin, const float* __restrict__ kin,
    const float* __restrict__ vin, const u16* __restrict__ Wb,
    const float* __restrict__ bv,
    float* __restrict__ out0, float* __restrict__ out1,
    float* __restrict__ out2) {
  // hk / hs / hv as bf16 [64 rows][128 cols], XOR-swizzled:
  // elem(row,c) at byte row*256 + ((c*2) ^ ((row&7)<<4))
  __shared__ __align__(16) u16 sH[3][MROWS * CC];

  const int tid = threadIdx.x;
  const int l = tid & 63;
  const int w = tid >> 6;
  const int n0 = blockIdx.x * NT;
  const int lr = l & 15;
  const int lg = l >> 4;

  // ---- projection phase: each wave owns rows [16w, 16w+16) ----
  const int arow = w * 16 + lr;                 // local row = agent*8 + nt
  const size_t grow_off =
      ((size_t)(arow >> 3) * NBATCH + (size_t)(n0 + (arow & 7))) * DDIM;

#pragma unroll
  for (int pj = 0; pj < 3; ++pj) {
    const float* X = (pj == 0) ? kin : ((pj == 1) ? qin : vin);
    const float* grow = X + grow_off;

    FragU fa[4];
#pragma unroll
    for (int kc = 0; kc < 4; ++kc) {
      const float4 x0 = *(const float4*)(grow + kc * 32 + lg * 4);
      const float4 x1 = *(const float4*)(grow + kc * 32 + lg * 4 + 16);
      s16x8 t;
      t[0] = (short)f2bf(x0.x); t[1] = (short)f2bf(x0.y);
      t[2] = (short)f2bf(x0.z); t[3] = (short)f2bf(x0.w);
      t[4] = (short)f2bf(x1.x); t[5] = (short)f2bf(x1.y);
      t[6] = (short)f2bf(x1.z); t[7] = (short)f2bf(x1.w);
      fa[kc].s = t;
    }

    f32x4 acc[8];
#pragma unroll
    for (int ct = 0; ct < 8; ++ct) acc[ct] = (f32x4)(0.0f);

#pragma unroll
    for (int ct = 0; ct < 8; ++ct) {
#pragma unroll
      for (int kc = 0; kc < 4; ++kc) {
        FragU fb;
        fb.s = *(const s16x8*)(Wb + ((((pj * 8 + ct) * 4 + kc) * 64 + l) << 3));
        acc[ct] = __builtin_amdgcn_mfma_f32_16x16x32_bf16(fa[kc].b, fb.b,
                                                          acc[ct], 0, 0, 0);
      }
    }

    // epilogue: D-frag lane l holds col=l&15(+16*ct), rows (l>>4)*4 + rg
    u16* dst = sH[pj];
#pragma unroll
    for (int ct = 0; ct < 8; ++ct) {
      const int c = ct * 16 + lr;
      float bias = 0.0f;
      if (pj == 2) bias = bv[c];
#pragma unroll
      for (int rg = 0; rg < 4; ++rg) {
        const int row = w * 16 + lg * 4 + rg;
        float x = acc[ct][rg];
        if (pj == 2) { x += bias; x = (x > 0.0f) ? x : 0.01f * x; }
        const int off = row * 256 + ((c * 2) ^ ((row & 7) << 4));
        *(u16*)((char*)dst + off) = f2bf(x);
      }
    }
  }

  __syncthreads();

  // ---- attention phase: thread = (h=w, i=l>>3, nt=l&7) ----
  const int h = w;
  const int i = l >> 3;
  const int nt = l & 7;
  const int n = n0 + nt;
  const int cb2 = h * 64;  // byte offset of col base h*32

  float hsv[32];
  {
    const int r = i * 8 + nt;
    const int swz = (r & 7) << 4;
#pragma unroll
    for (int qc = 0; qc < 4; ++qc) {
      s16x8 ch = *(const s16x8*)((const char*)sH[1] + r * 256 +
                                 ((cb2 + qc * 16) ^ swz));
#pragma unroll
      for (int e = 0; e < 8; ++e) hsv[qc * 8 + e] = bf2f((u16)(u32)(int)ch[e] & 0xFFFFu);
    }
  }

  float logits[8];
#pragma unroll
  for (int j = 0; j < 8; ++j) {
    const int r = j * 8 + nt;
    const int swz = (r & 7) << 4;
    float a = 0.0f;
#pragma unroll
    for (int qc = 0; qc < 4; ++qc) {
      s16x8 ch = *(const s16x8*)((const char*)sH[0] + r * 256 +
                                 ((cb2 + qc * 16) ^ swz));
#pragma unroll
      for (int e = 0; e < 8; ++e)
        a = fmaf(hsv[qc * 8 + e], bf2f((u16)(u32)(int)ch[e] & 0xFFFFu), a);
    }
    logits[j] = a;
  }

  const float scale = 0.17677669529663687f;  // 1/sqrt(32)
  float sl[8];
#pragma unroll
  for (int j = 0; j < 8; ++j) sl[j] = (j == i) ? -1e30f : logits[j] * scale;
  float m = sl[0];
#pragma unroll
  for (int j = 1; j < 8; ++j) m = fmaxf(m, sl[j]);
  float p[8];
  float s = 0.0f;
#pragma unroll
  for (int j = 0; j < 8; ++j) { p[j] = __expf(sl[j] - m); s += p[j]; }
  const float inv = 1.0f / s;

  const size_t ob = ((size_t)(i * HEADS + h) * NBATCH + (size_t)n);
  const size_t ob7 = ob * 7;
#pragma unroll
  for (int j = 0; j < 8; ++j) {
    if (j != i) {
      const int jj = j - ((j > i) ? 1 : 0);
      out1[ob7 + jj] = logits[j];      // UNSCALED logits (reference semantics)
      out2[ob7 + jj] = p[j] * inv;
    }
  }

  float oacc[32];
#pragma unroll
  for (int e = 0; e < 32; ++e) oacc[e] = 0.0f;
#pragma unroll
  for (int j = 0; j < 8; ++j) {
    const float pw = p[j] * inv;       // pw == 0 for j == i
    const int r = j * 8 + nt;
    const int swz = (r & 7) << 4;
#pragma unroll
    for (int qc = 0; qc < 4; ++qc) {
      s16x8 ch = *(const s16x8*)((const char*)sH[2] + r * 256 +
                                 ((cb2 + qc * 16) ^ swz));
#pragma unroll
      for (int e = 0; e < 8; ++e)
        oacc[qc * 8 + e] = fmaf(pw, bf2f((u16)(u32)(int)ch[e] & 0xFFFFu),
                                oacc[qc * 8 + e]);
    }
  }

  const size_t o0 = ob * 32;
#pragma unroll
  for (int qc = 0; qc < 8; ++qc) {
    float4 vv = make_float4(oacc[qc * 4 + 0], oacc[qc * 4 + 1],
                            oacc[qc * 4 + 2], oacc[qc * 4 + 3]);
    *(float4*)(out0 + o0 + qc * 4) = vv;
  }
}

extern "C" void kernel_launch(void* const* d_in, const int* in_sizes, int n_in,
                              void* d_out, int out_size, void* d_ws,
                              size_t ws_size, hipStream_t stream) {
  const float* qin = (const float*)d_in[0];
  const float* kin = (const float*)d_in[1];
  const float* vin = (const float*)d_in[2];
  const float* Wk  = (const float*)d_in[3];
  const float* Ws  = (const float*)d_in[4];
  const float* Wv  = (const float*)d_in[5];
  const float* bvp = (const float*)d_in[6];

  float* out0 = (float*)d_out;
  float* out1 = out0 + (size_t)AGT * HEADS * NBATCH * KDIM;
  float* out2 = out1 + (size_t)AGT * HEADS * NBATCH * 7;

  u16* Wb = (u16*)d_ws;  // 98304 bytes needed

  prep_weights<<<dim3(192), dim3(256), 0, stream>>>(Wk, Ws, Wv, Wb);
  fused_attn<<<dim3(NBATCH / NT), dim3(256), 0, stream>>>(
      qin, kin, vin, Wb, bvp, out0, out1, out2);
}